// Round 11
// baseline (74.884 us; speedup 1.0000x reference)
//
#include <hip/hip_runtime.h>
#include <hip/hip_bf16.h>
#include <math.h>

using f32x4 = __attribute__((ext_vector_type(4))) float;
using s16x8 = __attribute__((ext_vector_type(8))) short;
using s16x4 = __attribute__((ext_vector_type(4))) short;

#define LOG2E 1.44269504f

__device__ __forceinline__ unsigned short f2bf(float f) {
  unsigned int u = __builtin_bit_cast(unsigned int, f);
  u += 0x7FFFu + ((u >> 16) & 1u);
  return (unsigned short)(u >> 16);
}
__device__ __forceinline__ float lrelu(float v) { return v > 0.f ? v : 0.01f * v; }

__device__ __forceinline__ unsigned packbf(float lo, float hi) {
  return __builtin_amdgcn_perm(__builtin_bit_cast(unsigned, hi),
                               __builtin_bit_cast(unsigned, lo), 0x07060302u);
}
__device__ __forceinline__ float redsum_lh(float x) {
  x += __shfl_xor(x, 16);
  x += __shfl_xor(x, 32);
  return x;
}
// bit-transposition (lane-bit X <-> register-pair bit). R7/R9-PROVEN.
__device__ __forceinline__ void xswap(unsigned& A, unsigned& B, int X) {
  const int lane = (int)(threadIdx.x & 63);
  unsigned sel = (lane & X) ? A : B;
  unsigned ex = (unsigned)__shfl_xor((int)sel, X);
  A = (lane & X) ? ex : A;
  B = (lane & X) ? B : ex;
}

#define GLL16(src, dst)                                                        \
  __builtin_amdgcn_global_load_lds(                                            \
      (const __attribute__((address_space(1))) void*)(src),                    \
      (__attribute__((address_space(3))) void*)(dst), 16, 0, 0)

// ---------------------------------------------------------------------------
// Kernel 1: x1t[n][c], x2t[n][c] (x2 pre-scaled by log2e), x3[c][n] (bf16)
// grid 512 (b*128 + nchunk32), block 256.  (unchanged)
// ---------------------------------------------------------------------------
__global__ __launch_bounds__(256) void k1_conv3(
    const float* __restrict__ x,
    const float* __restrict__ W1, const float* __restrict__ b1,
    const float* __restrict__ W2, const float* __restrict__ b2,
    const float* __restrict__ W3, const float* __restrict__ b3,
    unsigned short* __restrict__ x1t, unsigned short* __restrict__ x2t,
    unsigned short* __restrict__ x3) {
  __shared__ float Wt[3][64][65];
  __shared__ alignas(16) float sX[64][36];
  __shared__ float sB[64][33];
  const int t = threadIdx.x;
  const int b = blockIdx.x >> 7;
  const int n0 = (blockIdx.x & 127) << 5;

  const float* Ws[3] = {W1, W2, W3};
  for (int e = t; e < 12288; e += 256) {
    const int w = e >> 12, idx = e & 4095;
    Wt[w][idx & 63][idx >> 6] = Ws[w][idx];
  }
#pragma unroll
  for (int r = 0; r < 2; ++r) {
    const int idx = t + r * 256;
    const int k = idx >> 3, q = idx & 7;
    *(float4*)&sX[k][q * 4] = *(const float4*)(x + ((size_t)b * 64 + k) * 4096 + n0 + q * 4);
  }
  __syncthreads();

  const int c = t & 63, g = t >> 6;
  float y1[8], y2[8], y3[8];
  const float bb1 = b1[c], bb2 = b2[c], bb3 = b3[c];
#pragma unroll
  for (int j = 0; j < 8; ++j) { y1[j] = bb1; y2[j] = bb2; y3[j] = bb3; }

  for (int k = 0; k < 64; ++k) {
    const float w1 = Wt[0][k][c], w2 = Wt[1][k][c], w3 = Wt[2][k][c];
#pragma unroll
    for (int j = 0; j < 8; ++j) {
      const float xs = sX[k][g * 8 + j];
      y1[j] = __builtin_fmaf(w1, xs, y1[j]);
      y2[j] = __builtin_fmaf(w2, xs, y2[j]);
      y3[j] = __builtin_fmaf(w3, xs, y3[j]);
    }
  }
#pragma unroll
  for (int j = 0; j < 8; ++j) {
    const size_t n = (size_t)n0 + g * 8 + j;
    x1t[((size_t)b * 4096 + n) * 64 + c] = f2bf(lrelu(y1[j]));
    x2t[((size_t)b * 4096 + n) * 64 + c] = f2bf(lrelu(y2[j]) * LOG2E);
    sB[c][g * 8 + j] = lrelu(y3[j]);
  }
  __syncthreads();
  {
    const int c2 = t >> 2, q = t & 3;
    s16x8 v;
#pragma unroll
    for (int jj = 0; jj < 8; ++jj) v[jj] = (short)f2bf(sB[c2][q * 8 + jj]);
    *(s16x8*)(x3 + ((size_t)b * 64 + c2) * 4096 + n0 + q * 8) = v;
  }
}

// ---------------------------------------------------------------------------
// Kernel 2: flash attention, 32-m tiles, wave-private single-buffer K/V,
// zero loop barriers, 2 blocks/CU (64KB LDS, VGPR<=128).
// grid 512 = (b, mtile32). block 512 = 8 waves; wave w owns n slice
// [w*512,(w+1)*512), 16 steps of 32n. Order per step: vmcnt(0) [tile ready]
// -> ds_read frags -> lgkmcnt(0) -> issue next GLLs -> compute.
// Epilogue: 3-round LDS tree reduce (8->4->2->1) + W4 conv + residual.
// LDS: staging 8x8KB=64KB; epilogue overlay R0..R3 [32][65]f32 @ i*8448,
// sL @33792, W4 [64][68] @34816 (end 52224), attnS overlays R2 @16896.
// ---------------------------------------------------------------------------
#define SLOFF 33792
#define W4OFF 34816
#define ATOFF 16896
#define SMSZ 65536

__global__ __launch_bounds__(512, 4) void k2_attn_fused(
    const unsigned short* __restrict__ x1t,
    const unsigned short* __restrict__ x2t,
    const unsigned short* __restrict__ x3,
    const float* __restrict__ W4, const float* __restrict__ b4,
    const float* __restrict__ x, float* __restrict__ out) {
  __shared__ __align__(16) char SM[SMSZ];
  char* smB = (char*)SM;

  const int t = threadIdx.x;
  const int wave = t >> 6, lane = t & 63;
  const int l15 = lane & 15, lh = lane >> 4;
  const int b = blockIdx.x >> 7;
  const int m0 = (blockIdx.x & 127) << 5;
  const int nb = wave * 512; // this wave's private n-slice

  const char* x1B = (const char*)(x1t + (size_t)b * 4096 * 64); // [n][c] 128B rows
  const char* x3B = (const char*)(x3 + (size_t)b * 64 * 4096);  // [c][n] 8192B rows
  const unsigned short* x2b = x2t + (size_t)b * 4096 * 64;

  // wave-private LDS: K 4KB + V 4KB
  char* wK = smB + wave * 8192;
  char* wV = wK + 4096;

  // staging source offsets (pre-swizzled global source, linear LDS dest)
  int kSrcOff[4], vSrcOff[4];
#pragma unroll
  for (int i = 0; i < 4; ++i) {
    const int o = i * 1024 + lane * 16;
    {
      const int n = o >> 7, cb = (o & 127) ^ ((n & 7) << 4);
      kSrcOff[i] = n * 128 + cb;
    }
    {
      const int ch = o >> 7, rem = (o & 127) ^ ((ch & 7) << 4);
      vSrcOff[i] = (ch * 2 + (rem >> 6)) * 8192 + (rem & 63);
    }
  }

  // Q fragments (B-operand), persistent: 2 groups of 16 m
  s16x8 qf[2][2];
#pragma unroll
  for (int q2 = 0; q2 < 2; ++q2) {
    const unsigned short* qp = x2b + (size_t)(m0 + q2 * 16 + l15) * 64 + lh * 8;
    qf[q2][0] = *(const s16x8*)qp;
    qf[q2][1] = *(const s16x8*)(qp + 32);
  }

  f32x4 O[2][4];
#pragma unroll
  for (int q2 = 0; q2 < 2; ++q2)
#pragma unroll
    for (int s = 0; s < 4; ++s) O[q2][s] = (f32x4){0.f, 0.f, 0.f, 0.f};
  float l_part[2] = {0.f, 0.f};

  const int swzK = (l15 & 7) << 4;
  const int swzV = ((l15 >> 1) & 7) << 4;

  // prologue: stage tile 0
#pragma unroll
  for (int i = 0; i < 4; ++i) GLL16(x1B + (size_t)nb * 128 + kSrcOff[i], wK + i * 1024);
#pragma unroll
  for (int i = 0; i < 4; ++i) GLL16(x3B + (size_t)nb * 2 + vSrcOff[i], wV + i * 1024);

  for (int j = 0; j < 16; ++j) {
    // ---- current tile staged?
    asm volatile("s_waitcnt vmcnt(0)" ::: "memory");
    __builtin_amdgcn_sched_barrier(0);
    // ---- LDS fragment reads (wave-private)
    s16x8 kf[2][2], vf[4];
#pragma unroll
    for (int s2 = 0; s2 < 2; ++s2) {
      const char* kp = wK + (s2 * 16 + l15) * 128;
      kf[s2][0] = *(const s16x8*)(kp + ((lh * 16) ^ swzK));
      kf[s2][1] = *(const s16x8*)(kp + ((lh * 16 + 64) ^ swzK));
    }
#pragma unroll
    for (int s = 0; s < 4; ++s) {
      const int c = s * 16 + l15;
      vf[s] = *(const s16x8*)(wV + (c >> 1) * 128 + (((c & 1) * 64 + lh * 16) ^ swzV));
    }
    // ---- reads retired -> safe to overwrite buffer with next tile
    asm volatile("s_waitcnt lgkmcnt(0)" ::: "memory");
    __builtin_amdgcn_sched_barrier(0);
    if (j < 15) {
      const int tb = nb + (j + 1) * 32;
#pragma unroll
      for (int i = 0; i < 4; ++i) GLL16(x1B + (size_t)tb * 128 + kSrcOff[i], wK + i * 1024);
#pragma unroll
      for (int i = 0; i < 4; ++i) GLL16(x3B + (size_t)tb * 2 + vSrcOff[i], wV + i * 1024);
    }
    __builtin_amdgcn_sched_barrier(0);
    // ---- QK for both q2 (wide ILP)
    f32x4 S[2][2];
#pragma unroll
    for (int q2 = 0; q2 < 2; ++q2)
#pragma unroll
      for (int s2 = 0; s2 < 2; ++s2) {
        f32x4 z = {0.f, 0.f, 0.f, 0.f};
        z = __builtin_amdgcn_mfma_f32_16x16x32_bf16(kf[s2][0], qf[q2][0], z, 0, 0, 0);
        S[q2][s2] = __builtin_amdgcn_mfma_f32_16x16x32_bf16(kf[s2][1], qf[q2][1], z, 0, 0, 0);
      }
    // ---- 32 independent exp2 + partial sums
    float pr[2][2][4];
#pragma unroll
    for (int q2 = 0; q2 < 2; ++q2) {
      float ts = 0.f;
#pragma unroll
      for (int s2 = 0; s2 < 2; ++s2)
#pragma unroll
        for (int r = 0; r < 4; ++r) {
          pr[q2][s2][r] = __builtin_amdgcn_exp2f(S[q2][s2][r]);
          ts += pr[q2][s2][r];
        }
      l_part[q2] += ts;
    }
    // ---- transpose (two independent chains) + PV
#pragma unroll
    for (int q2 = 0; q2 < 2; ++q2) {
      unsigned u00 = packbf(pr[q2][0][0], pr[q2][0][1]), u01 = packbf(pr[q2][0][2], pr[q2][0][3]);
      unsigned u10 = packbf(pr[q2][1][0], pr[q2][1][1]), u11 = packbf(pr[q2][1][2], pr[q2][1][3]);
      xswap(u00, u10, 32); xswap(u01, u11, 32); // (L5 <-> W1)
      xswap(u00, u10, 16); xswap(u01, u11, 16); // (L4 <-> W1)
      int4 w = {(int)u00, (int)u01, (int)u10, (int)u11};
      s16x8 pf = __builtin_bit_cast(s16x8, w);
#pragma unroll
      for (int s = 0; s < 4; ++s)
        O[q2][s] = __builtin_amdgcn_mfma_f32_16x16x32_bf16(vf[s], pf, O[q2][s], 0, 0, 0);
    }
  }

  // ---- epilogue: tree-reduce 8 waves' partials (regions overlay dead staging)
  auto Rp = [&](int i) { return (float*)(smB + i * 8448); }; // [32m][65c]
  float* sLf = (float*)(smB + SLOFF);                        // [8][32]
  float* Wt4 = (float*)(smB + W4OFF);                        // [64][68]
  auto writeO = [&](float* R) {
#pragma unroll
    for (int q2 = 0; q2 < 2; ++q2)
#pragma unroll
      for (int s = 0; s < 4; ++s)
#pragma unroll
        for (int r = 0; r < 4; ++r)
          R[(q2 * 16 + l15) * 65 + s * 16 + lh * 4 + r] = O[q2][s][r];
  };
  auto addO = [&](const float* R) {
#pragma unroll
    for (int q2 = 0; q2 < 2; ++q2)
#pragma unroll
      for (int s = 0; s < 4; ++s)
#pragma unroll
        for (int r = 0; r < 4; ++r)
          O[q2][s][r] += R[(q2 * 16 + l15) * 65 + s * 16 + lh * 4 + r];
  };

  __syncthreads(); // (A) all main loops done; staging dead
  for (int e = t; e < 4096; e += 512) Wt4[(e & 63) * 68 + (e >> 6)] = W4[e];
#pragma unroll
  for (int q2 = 0; q2 < 2; ++q2) {
    const float l = redsum_lh(l_part[q2]);
    if (lh == 0) sLf[wave * 32 + q2 * 16 + l15] = l;
  }
  if (wave >= 4) writeO(Rp(wave - 4));
  __syncthreads(); // (B)
  if (wave < 4) addO(Rp(wave));
  __syncthreads(); // (C)
  if (wave == 2 || wave == 3) writeO(Rp(wave - 2));
  __syncthreads(); // (D)
  if (wave < 2) addO(Rp(wave));
  __syncthreads(); // (E)
  if (wave == 1) writeO(Rp(0));
  __syncthreads(); // (F)
  float* attnS = (float*)(smB + ATOFF); // [64c][33m], overlays dead R2
  if (wave == 0) {
    addO(Rp(0));
#pragma unroll
    for (int q2 = 0; q2 < 2; ++q2) {
      float den = 0.f;
#pragma unroll
      for (int w = 0; w < 8; ++w) den += sLf[w * 32 + q2 * 16 + l15];
      const float inv = 1.f / den;
#pragma unroll
      for (int s = 0; s < 4; ++s)
#pragma unroll
        for (int r = 0; r < 4; ++r)
          attnS[(s * 16 + lh * 4 + r) * 33 + q2 * 16 + l15] = O[q2][s][r] * inv;
    }
  }
  __syncthreads(); // (G)

  // ---- conv4 + lrelu + residual: thread -> m=t&31, channels (t>>5)*4..+3
  const int mloc = t & 31, cq = t >> 5;
  const int co0 = cq * 4;
  float acc[4];
#pragma unroll
  for (int ci = 0; ci < 4; ++ci) acc[ci] = b4[co0 + ci];
  for (int k = 0; k < 64; ++k) {
    const float a = attnS[k * 33 + mloc];
    const float4 wv = *(const float4*)&Wt4[k * 68 + co0];
#pragma unroll
    for (int ci = 0; ci < 4; ++ci)
      acc[ci] = __builtin_fmaf(((const float*)&wv)[ci], a, acc[ci]);
  }
#pragma unroll
  for (int ci = 0; ci < 4; ++ci) {
    const size_t idx = ((size_t)b * 64 + co0 + ci) * 4096 + m0 + mloc;
    out[idx] = lrelu(acc[ci]) + x[idx];
  }
}

extern "C" void kernel_launch(void* const* d_in, const int* in_sizes, int n_in,
                              void* d_out, int out_size, void* d_ws, size_t ws_size,
                              hipStream_t stream) {
  const float* x = (const float*)d_in[0];
  const float* W1 = (const float*)d_in[1];
  const float* b1 = (const float*)d_in[2];
  const float* W2 = (const float*)d_in[3];
  const float* b2 = (const float*)d_in[4];
  const float* W3 = (const float*)d_in[5];
  const float* b3 = (const float*)d_in[6];
  const float* W4 = (const float*)d_in[7];
  const float* b4 = (const float*)d_in[8];
  float* out = (float*)d_out;

  const size_t planes = (size_t)4 * 4096 * 64; // 1M bf16 elems each
  unsigned short* x1t = (unsigned short*)d_ws;
  unsigned short* x2t = x1t + planes;
  unsigned short* x3 = x2t + planes;

  hipLaunchKernelGGL(k1_conv3, dim3(512), dim3(256), 0, stream,
                     x, W1, b1, W2, b2, W3, b3, x1t, x2t, x3);
  hipLaunchKernelGGL(k2_attn_fused, dim3(512), dim3(512), 0, stream,
                     x1t, x2t, x3, W4, b4, x, out);
}

// Round 12
// 72.610 us; speedup vs baseline: 1.0313x; 1.0313x over previous
//
#include <hip/hip_runtime.h>
#include <hip/hip_bf16.h>
#include <math.h>

using f32x4 = __attribute__((ext_vector_type(4))) float;
using s16x8 = __attribute__((ext_vector_type(8))) short;
using s16x4 = __attribute__((ext_vector_type(4))) short;

#define LOG2E 1.44269504f

__device__ __forceinline__ unsigned short f2bf(float f) {
  unsigned int u = __builtin_bit_cast(unsigned int, f);
  u += 0x7FFFu + ((u >> 16) & 1u);
  return (unsigned short)(u >> 16);
}
__device__ __forceinline__ float lrelu(float v) { return v > 0.f ? v : 0.01f * v; }

// pack two f32 -> one u32 of 2 bf16 (truncation; bias cancels in softmax ratio)
__device__ __forceinline__ unsigned packbf(float lo, float hi) {
  return __builtin_amdgcn_perm(__builtin_bit_cast(unsigned, hi),
                               __builtin_bit_cast(unsigned, lo), 0x07060302u);
}
__device__ __forceinline__ float redsum_lh(float x) {
  x += __shfl_xor(x, 16);
  x += __shfl_xor(x, 32);
  return x;
}

#define GLL16(src, dst)                                                        \
  __builtin_amdgcn_global_load_lds(                                            \
      (const __attribute__((address_space(1))) void*)(src),                    \
      (__attribute__((address_space(3))) void*)(dst), 16, 0, 0)

// ---------------------------------------------------------------------------
// Kernel 1: x1t[n][c], x2t[n][c] (x2 pre-scaled by log2e), x3[c][n] (bf16)
// grid 512 (b*128 + nchunk32), block 256.  (unchanged, proven)
// ---------------------------------------------------------------------------
__global__ __launch_bounds__(256) void k1_conv3(
    const float* __restrict__ x,
    const float* __restrict__ W1, const float* __restrict__ b1,
    const float* __restrict__ W2, const float* __restrict__ b2,
    const float* __restrict__ W3, const float* __restrict__ b3,
    unsigned short* __restrict__ x1t, unsigned short* __restrict__ x2t,
    unsigned short* __restrict__ x3) {
  __shared__ float Wt[3][64][65];
  __shared__ alignas(16) float sX[64][36];
  __shared__ float sB[64][33];
  const int t = threadIdx.x;
  const int b = blockIdx.x >> 7;
  const int n0 = (blockIdx.x & 127) << 5;

  const float* Ws[3] = {W1, W2, W3};
  for (int e = t; e < 12288; e += 256) {
    const int w = e >> 12, idx = e & 4095;
    Wt[w][idx & 63][idx >> 6] = Ws[w][idx];
  }
#pragma unroll
  for (int r = 0; r < 2; ++r) {
    const int idx = t + r * 256;
    const int k = idx >> 3, q = idx & 7;
    *(float4*)&sX[k][q * 4] = *(const float4*)(x + ((size_t)b * 64 + k) * 4096 + n0 + q * 4);
  }
  __syncthreads();

  const int c = t & 63, g = t >> 6;
  float y1[8], y2[8], y3[8];
  const float bb1 = b1[c], bb2 = b2[c], bb3 = b3[c];
#pragma unroll
  for (int j = 0; j < 8; ++j) { y1[j] = bb1; y2[j] = bb2; y3[j] = bb3; }

  for (int k = 0; k < 64; ++k) {
    const float w1 = Wt[0][k][c], w2 = Wt[1][k][c], w3 = Wt[2][k][c];
#pragma unroll
    for (int j = 0; j < 8; ++j) {
      const float xs = sX[k][g * 8 + j];
      y1[j] = __builtin_fmaf(w1, xs, y1[j]);
      y2[j] = __builtin_fmaf(w2, xs, y2[j]);
      y3[j] = __builtin_fmaf(w3, xs, y3[j]);
    }
  }
#pragma unroll
  for (int j = 0; j < 8; ++j) {
    const size_t n = (size_t)n0 + g * 8 + j;
    x1t[((size_t)b * 4096 + n) * 64 + c] = f2bf(lrelu(y1[j]));
    x2t[((size_t)b * 4096 + n) * 64 + c] = f2bf(lrelu(y2[j]) * LOG2E);
    sB[c][g * 8 + j] = lrelu(y3[j]);
  }
  __syncthreads();
  {
    const int c2 = t >> 2, q = t & 3;
    s16x8 v;
#pragma unroll
    for (int jj = 0; jj < 8; ++jj) v[jj] = (short)f2bf(sB[c2][q * 8 + jj]);
    *(s16x8*)(x3 + ((size_t)b * 64 + c2) * 4096 + n0 + q * 8) = v;
  }
}

// ---------------------------------------------------------------------------
// Kernel 2: flash attention, NO in-loop cross-lane ops.
// grid 256 = (b, mtile64). block 1024 = 16 waves = msub(2: 32m) x split(8: 512n).
// Wave-private DOUBLE-buffered 16n K/V tiles (8KB/wave): 32 tiles, unroll-2
// (even tile -> buf0, odd -> buf1), counted vmcnt(4) per half-step.
// KEY: 16n QK output layout (n=lh*4+r, m=l15) IS the PV B-fragment layout for
// a k-permuted K=32 MFMA: pf = {evenW0,evenW1,oddW0,oddW1}, vf = {b64(n),
// b64(n+16)} in the SAME permuted order -> contraction invariant, NO transpose.
// LDS: staging 16x8KB=131072 | W4 [64][68] @131072 | sL @148480. SMSZ=150528.
// Epilogue: R9-proven publish/merge/conv4/residual (cO+attnS overlay staging).
// ---------------------------------------------------------------------------
#define W4OFF 131072
#define SLOFF 148480
#define SMSZ 150528

__global__ __launch_bounds__(1024, 4) void k2_attn_fused(
    const unsigned short* __restrict__ x1t,
    const unsigned short* __restrict__ x2t,
    const unsigned short* __restrict__ x3,
    const float* __restrict__ W4, const float* __restrict__ b4,
    const float* __restrict__ x, float* __restrict__ out) {
  __shared__ __align__(16) char SM[SMSZ];
  char* smB = (char*)SM;

  const int t = threadIdx.x;
  const int wave = t >> 6, lane = t & 63;
  const int l15 = lane & 15, lh = lane >> 4;
  const int msub = wave & 1, split = wave >> 1;
  const int b = blockIdx.x >> 6;
  const int m0 = (blockIdx.x & 63) << 6;
  const int nb = split * 512; // wave's private n-slice (32 tiles of 16)

  const char* x1B = (const char*)(x1t + (size_t)b * 4096 * 64); // [n][c] 128B rows
  const char* x3B = (const char*)(x3 + (size_t)b * 64 * 4096);  // [c][n] 8192B rows
  const unsigned short* x2b = x2t + (size_t)b * 4096 * 64;

  // W4 -> LDS transposed (disjoint region)
  {
    float* Wt4 = (float*)(smB + W4OFF);
    for (int e = t; e < 4096; e += 1024) Wt4[(e & 63) * 68 + (e >> 6)] = W4[e];
  }

  // wave-private buffers: K0,K1 (2KB each), V0,V1 (2KB each)
  char* wK0 = smB + wave * 8192;
  char* wK1 = wK0 + 2048;
  char* wV0 = wK0 + 4096;
  char* wV1 = wK0 + 6144;

  // ---- staging source offsets (pre-swizzled global src, linear LDS dest) ----
  // K tile (16n x 128B), phys(n, cb) = n*128 + (cb ^ ((n&7)<<4)).
  // GLL i covers rows n = i*8 + (l>>3), seg (l&7)*16.
  const int krow = lane >> 3, kseg = lane & 7;
  const int kSrcBase = krow * 128 + ((kseg * 16) ^ (krow << 4)); // + i*1024 + n0*128
  // V tile: nat(c,n) = (c&15)*128 + (c>>4)*32 + n*2, phys = row + (rem ^ ((cr&7)<<4)).
  // GLL i: chunk l' = i*64 + l: cr = l'>>3 (i*8 + l>>3), rem = (l&7)*16,
  // nat_rem = rem ^ (( (l>>3) )<<4) -> cgr = nat>>5, h = (nat>>4)&1.
  int vSrcBase[2];
#pragma unroll
  for (int i = 0; i < 2; ++i) {
    const int cr = i * 8 + (lane >> 3);
    const int nat = ((lane & 7) * 16) ^ ((cr & 7) << 4);
    const int cgr = nat >> 5, h = (nat >> 4) & 1;
    vSrcBase[i] = (cgr * 16 + cr) * 8192 + h * 16; // + n0*2
  }

  // Q fragments (B-operand), persistent: 2 groups of 16 m
  s16x8 qf[2][2];
#pragma unroll
  for (int q2 = 0; q2 < 2; ++q2) {
    const unsigned short* qp = x2b + (size_t)(m0 + msub * 32 + q2 * 16 + l15) * 64 + lh * 8;
    qf[q2][0] = *(const s16x8*)qp;
    qf[q2][1] = *(const s16x8*)(qp + 32);
  }

  f32x4 O[2][4];
#pragma unroll
  for (int q2 = 0; q2 < 2; ++q2)
#pragma unroll
    for (int s = 0; s < 4; ++s) O[q2][s] = (f32x4){0.f, 0.f, 0.f, 0.f};
  float l_part[2] = {0.f, 0.f};

  const int swzR = (l15 & 7) << 4; // read swizzle (row = l15 for both K and V)

  // prologue: stage tiles 0 (buf0) and 1 (buf1): 8 GLL outstanding
  {
    const int nA = nb, nB = nb + 16;
    GLL16(x1B + (size_t)nA * 128 + kSrcBase, wK0);
    GLL16(x1B + (size_t)nA * 128 + kSrcBase + 1024, wK0 + 1024);
    GLL16(x3B + (size_t)nA * 2 + vSrcBase[0], wV0);
    GLL16(x3B + (size_t)nA * 2 + vSrcBase[1], wV0 + 1024);
    GLL16(x1B + (size_t)nB * 128 + kSrcBase, wK1);
    GLL16(x1B + (size_t)nB * 128 + kSrcBase + 1024, wK1 + 1024);
    GLL16(x3B + (size_t)nB * 2 + vSrcBase[0], wV1);
    GLL16(x3B + (size_t)nB * 2 + vSrcBase[1], wV1 + 1024);
  }

  s16x4 vfe[4];          // even-tile V b64 frags
  unsigned we[2][2];     // even-tile packed P words per q2

  for (int j2 = 0; j2 < 16; ++j2) {
    // ================= EVEN half-step (buf0, tile 2*j2) =================
    asm volatile("s_waitcnt vmcnt(4)" ::: "memory");
    __builtin_amdgcn_sched_barrier(0);
    s16x8 kf0, kf1;
    {
      const char* kp = wK0 + l15 * 128;
      kf0 = *(const s16x8*)(kp + ((lh * 16) ^ swzR));
      kf1 = *(const s16x8*)(kp + ((lh * 16 + 64) ^ swzR));
    }
#pragma unroll
    for (int s = 0; s < 4; ++s)
      vfe[s] = *(const s16x4*)(wV0 + l15 * 128 + (((s * 32 + lh * 8)) ^ swzR));
    asm volatile("s_waitcnt lgkmcnt(0)" ::: "memory");
    __builtin_amdgcn_sched_barrier(0);
    if (j2 < 15) { // stage tile 2*j2+2 -> buf0
      const int nn = nb + (2 * j2 + 2) * 16;
      GLL16(x1B + (size_t)nn * 128 + kSrcBase, wK0);
      GLL16(x1B + (size_t)nn * 128 + kSrcBase + 1024, wK0 + 1024);
      GLL16(x3B + (size_t)nn * 2 + vSrcBase[0], wV0);
      GLL16(x3B + (size_t)nn * 2 + vSrcBase[1], wV0 + 1024);
    }
    __builtin_amdgcn_sched_barrier(0);
#pragma unroll
    for (int q2 = 0; q2 < 2; ++q2) {
      f32x4 z = {0.f, 0.f, 0.f, 0.f};
      z = __builtin_amdgcn_mfma_f32_16x16x32_bf16(kf0, qf[q2][0], z, 0, 0, 0);
      z = __builtin_amdgcn_mfma_f32_16x16x32_bf16(kf1, qf[q2][1], z, 0, 0, 0);
      float p0 = __builtin_amdgcn_exp2f(z[0]), p1 = __builtin_amdgcn_exp2f(z[1]);
      float p2 = __builtin_amdgcn_exp2f(z[2]), p3 = __builtin_amdgcn_exp2f(z[3]);
      l_part[q2] += (p0 + p1) + (p2 + p3);
      we[q2][0] = packbf(p0, p1);
      we[q2][1] = packbf(p2, p3);
    }
    // ================= ODD half-step (buf1, tile 2*j2+1) =================
    if (j2 < 15) {
      asm volatile("s_waitcnt vmcnt(4)" ::: "memory");
    } else {
      asm volatile("s_waitcnt vmcnt(0)" ::: "memory");
    }
    __builtin_amdgcn_sched_barrier(0);
    s16x8 kf0o, kf1o;
    {
      const char* kp = wK1 + l15 * 128;
      kf0o = *(const s16x8*)(kp + ((lh * 16) ^ swzR));
      kf1o = *(const s16x8*)(kp + ((lh * 16 + 64) ^ swzR));
    }
    s16x4 vfo[4];
#pragma unroll
    for (int s = 0; s < 4; ++s)
      vfo[s] = *(const s16x4*)(wV1 + l15 * 128 + (((s * 32 + lh * 8)) ^ swzR));
    asm volatile("s_waitcnt lgkmcnt(0)" ::: "memory");
    __builtin_amdgcn_sched_barrier(0);
    if (j2 < 15) { // stage tile 2*j2+3 -> buf1
      const int nn = nb + (2 * j2 + 3) * 16;
      GLL16(x1B + (size_t)nn * 128 + kSrcBase, wK1);
      GLL16(x1B + (size_t)nn * 128 + kSrcBase + 1024, wK1 + 1024);
      GLL16(x3B + (size_t)nn * 2 + vSrcBase[0], wV1);
      GLL16(x3B + (size_t)nn * 2 + vSrcBase[1], wV1 + 1024);
    }
    __builtin_amdgcn_sched_barrier(0);
#pragma unroll
    for (int q2 = 0; q2 < 2; ++q2) {
      f32x4 z = {0.f, 0.f, 0.f, 0.f};
      z = __builtin_amdgcn_mfma_f32_16x16x32_bf16(kf0o, qf[q2][0], z, 0, 0, 0);
      z = __builtin_amdgcn_mfma_f32_16x16x32_bf16(kf1o, qf[q2][1], z, 0, 0, 0);
      float p0 = __builtin_amdgcn_exp2f(z[0]), p1 = __builtin_amdgcn_exp2f(z[1]);
      float p2 = __builtin_amdgcn_exp2f(z[2]), p3 = __builtin_amdgcn_exp2f(z[3]);
      l_part[q2] += (p0 + p1) + (p2 + p3);
      // ---- PV over the 32n pair, k-permuted fragments (no transpose) ----
      int4 pw = {(int)we[q2][0], (int)we[q2][1], (int)packbf(p0, p1), (int)packbf(p2, p3)};
      s16x8 pf = __builtin_bit_cast(s16x8, pw);
#pragma unroll
      for (int s = 0; s < 4; ++s) {
        s16x8 vf;
#pragma unroll
        for (int e = 0; e < 4; ++e) { vf[e] = vfe[s][e]; vf[e + 4] = vfo[s][e]; }
        O[q2][s] = __builtin_amdgcn_mfma_f32_16x16x32_bf16(vf, pf, O[q2][s], 0, 0, 0);
      }
    }
  }

  // ---- epilogue (R9-proven): publish fp32 partials over dead staging LDS
  __syncthreads(); // all waves' main loops done
  float* cOf = (float*)smB;           // [16][32][64] = 128KB
  float* sLf = (float*)(smB + SLOFF); // [16][32]
#pragma unroll
  for (int q2 = 0; q2 < 2; ++q2) {
    const float l = redsum_lh(l_part[q2]);
    const int m32 = q2 * 16 + l15;
    if (lh == 0) sLf[wave * 32 + m32] = l;
#pragma unroll
    for (int s = 0; s < 4; ++s)
      *(f32x4*)(cOf + wave * 2048 + m32 * 64 + s * 16 + lh * 4) = O[q2][s];
  }
  __syncthreads();

  // ---- merge 16 waves (8 splits x 2 msub): thread -> m=t&63, cq=t>>6
  const int mloc = t & 63, cq = t >> 6;
  const int msub2 = mloc >> 5, m32b = mloc & 31;
  float den = 0.f, num[4] = {0.f, 0.f, 0.f, 0.f};
#pragma unroll
  for (int s2 = 0; s2 < 8; ++s2) {
    const int w = msub2 + 2 * s2;
    den += sLf[w * 32 + m32b];
    const f32x4 cv = *(const f32x4*)(cOf + w * 2048 + m32b * 64 + cq * 4);
#pragma unroll
    for (int jj = 0; jj < 4; ++jj) num[jj] += cv[jj];
  }
  const float inv = 1.f / den;
  __syncthreads(); // cO reads done -> overlay attnS
  float* attnS = (float*)smB; // [64][65]
#pragma unroll
  for (int jj = 0; jj < 4; ++jj) attnS[(cq * 4 + jj) * 65 + mloc] = num[jj] * inv;
  __syncthreads();

  // ---- conv4 + lrelu + residual
  const float* Wt4 = (const float*)(smB + W4OFF); // [64][68]
  const int co0 = cq * 4;
  float acc[4];
#pragma unroll
  for (int ci = 0; ci < 4; ++ci) acc[ci] = b4[co0 + ci];
  for (int k = 0; k < 64; ++k) {
    const float a = attnS[k * 65 + mloc];
    const float4 wv = *(const float4*)&Wt4[k * 68 + co0];
#pragma unroll
    for (int ci = 0; ci < 4; ++ci)
      acc[ci] = __builtin_fmaf(((const float*)&wv)[ci], a, acc[ci]);
  }
#pragma unroll
  for (int ci = 0; ci < 4; ++ci) {
    const size_t idx = ((size_t)b * 64 + co0 + ci) * 4096 + m0 + mloc;
    out[idx] = lrelu(acc[ci]) + x[idx];
  }
}

extern "C" void kernel_launch(void* const* d_in, const int* in_sizes, int n_in,
                              void* d_out, int out_size, void* d_ws, size_t ws_size,
                              hipStream_t stream) {
  const float* x = (const float*)d_in[0];
  const float* W1 = (const float*)d_in[1];
  const float* b1 = (const float*)d_in[2];
  const float* W2 = (const float*)d_in[3];
  const float* b2 = (const float*)d_in[4];
  const float* W3 = (const float*)d_in[5];
  const float* b3 = (const float*)d_in[6];
  const float* W4 = (const float*)d_in[7];
  const float* b4 = (const float*)d_in[8];
  float* out = (float*)d_out;

  const size_t planes = (size_t)4 * 4096 * 64; // 1M bf16 elems each
  unsigned short* x1t = (unsigned short*)d_ws;
  unsigned short* x2t = x1t + planes;
  unsigned short* x3 = x2t + planes;

  hipLaunchKernelGGL(k1_conv3, dim3(512), dim3(256), 0, stream,
                     x, W1, b1, W2, b2, W3, b3, x1t, x2t, x3);
  hipLaunchKernelGGL(k2_attn_fused, dim3(256), dim3(1024), 0, stream,
                     x1t, x2t, x3, W4, b4, x, out);
}